// Round 1
// baseline (370.731 us; speedup 1.0000x reference)
//
#include <hip/hip_runtime.h>

static constexpr int S_SYS  = 8;
static constexpr int E_PAIRS = 1000000;
static constexpr int N_A    = 20000;
static constexpr int NBINS  = 16;

// Kernel 1: per-pair switching function -> scatter-add onto per-system coords.
// 4 pairs per thread so the [S,E,3] f32 layout reads as 3 coalesced float4 +
// 1 int4 per thread (16B/lane).
__global__ __launch_bounds__(256) void coord_scatter(
    const float* __restrict__ vec, const int* __restrict__ atom,
    float* __restrict__ coords)
{
    const int P4 = S_SYS * E_PAIRS / 4;   // 2,000,000 thread-work items
    int stride = gridDim.x * blockDim.x;
    for (int t = blockIdx.x * blockDim.x + threadIdx.x; t < P4; t += stride) {
        const float4* v4 = reinterpret_cast<const float4*>(vec) + 3ull * (unsigned)t;
        float4 A = v4[0], B = v4[1], C = v4[2];
        int4 id = reinterpret_cast<const int4*>(atom)[t];

        // E_PAIRS % 4 == 0 so a 4-pair group never crosses a system boundary
        int s = (t * 4) / E_PAIRS;
        float* cs = coords + s * N_A;

        float px[4] = {A.x, A.w, B.z, C.y};
        float py[4] = {A.y, B.x, B.w, C.z};
        float pz[4] = {A.z, B.y, C.x, C.w};
        int ids[4]  = {id.x, id.y, id.z, id.w};

        #pragma unroll
        for (int j = 0; j < 4; ++j) {
            float d = sqrtf(px[j]*px[j] + py[j]*py[j] + pz[j]*pz[j]);
            // y = (d - R1) / (R0 - R1), R1 = 4.4, R0 = 5.5 (division to match ref rounding)
            float y = (d - 4.4f) / 1.1f;
            float z;
            if (y <= 0.0f)      z = 1.0f;
            else if (y >= 1.0f) z = 0.0f;
            else { float u = y - 1.0f; z = u * u * (1.0f + 2.0f * y); }
            if (z != 0.0f) atomicAdd(&cs[ids[j]], z);   // skip ~18% zero adds
        }
    }
}

// Kernel 2: KDE histogram. One block = 256 atoms of one system.
// Per-thread 16 expf, wave shuffle-reduce, LDS combine, 16 global atomics/block.
__global__ __launch_bounds__(256) void kde_reduce(
    const float* __restrict__ coords, float* __restrict__ out)
{
    int s = blockIdx.y;
    int a = blockIdx.x * 256 + threadIdx.x;
    bool valid = (a < N_A);
    float c = valid ? coords[s * N_A + a] : 0.0f;

    float vals[NBINS];
    #pragma unroll
    for (int k = 0; k < NBINS; ++k) {
        float d = c - (float)k;
        vals[k] = valid ? expf(-2.0f * d * d) : 0.0f;   // 0.5/SIGMA2 == 2 exactly
    }

    // 64-lane butterfly reduce each bin
    #pragma unroll
    for (int k = 0; k < NBINS; ++k) {
        #pragma unroll
        for (int off = 32; off > 0; off >>= 1)
            vals[k] += __shfl_down(vals[k], off, 64);
    }

    __shared__ float sbin[4][NBINS];
    int wave = threadIdx.x >> 6;
    int lane = threadIdx.x & 63;
    if (lane == 0) {
        #pragma unroll
        for (int k = 0; k < NBINS; ++k) sbin[wave][k] = vals[k];
    }
    __syncthreads();
    if (threadIdx.x < NBINS) {
        float v = sbin[0][threadIdx.x] + sbin[1][threadIdx.x]
                + sbin[2][threadIdx.x] + sbin[3][threadIdx.x];
        atomicAdd(&out[s * NBINS + threadIdx.x], v);
    }
}

extern "C" void kernel_launch(void* const* d_in, const int* in_sizes, int n_in,
                              void* d_out, int out_size, void* d_ws, size_t ws_size,
                              hipStream_t stream) {
    const float* vec  = (const float*)d_in[0];   // neighbor_vectors [S,E,3] f32
    const int*   atom = (const int*)d_in[1];     // first_atom [S,E] i32
    float* out    = (float*)d_out;               // [S,16] f32
    float* coords = (float*)d_ws;                // [S, N_A] f32 scratch

    // harness poisons ws/out once; we must zero them every call
    hipMemsetAsync(coords, 0, (size_t)S_SYS * N_A * sizeof(float), stream);
    hipMemsetAsync(out,    0, (size_t)S_SYS * NBINS * sizeof(float), stream);

    coord_scatter<<<2048, 256, 0, stream>>>(vec, atom, coords);

    dim3 g2((N_A + 255) / 256, S_SYS);
    kde_reduce<<<g2, 256, 0, stream>>>(coords, out);
}